// Round 10
// baseline (242.822 us; speedup 1.0000x reference)
//
#include <hip/hip_runtime.h>
#include <hip/hip_fp16.h>

constexpr int S_LEN  = 2048;
constexpr int HID    = 1024;
constexpr int HEADS  = 16;
constexpr int HDIM   = 64;
constexpr int BATCH  = 2;
constexpr int BH     = BATCH * HEADS;          // 32
constexpr int M_ROWS = BATCH * S_LEN;          // 4096

typedef _Float16 half8  __attribute__((ext_vector_type(8)));
typedef _Float16 half4v __attribute__((ext_vector_type(4)));
typedef _Float16 half2v __attribute__((ext_vector_type(2)));
typedef float    f32x4  __attribute__((ext_vector_type(4)));
typedef float    f32x16 __attribute__((ext_vector_type(16)));
typedef unsigned uint4v __attribute__((ext_vector_type(4)));

constexpr float EXP2_OFF = -11.541560327111707f;   // -8*log2(e)
constexpr float Q_SCALE  = 0.18033688011112042f;   // 0.125*log2(e)

// ---------------------------------------------------------------------------
// Kernel 0: fp32 -> fp16 convert for X, Wq, Wk, Wv; mask -> fp32 exp2-bias.
// ---------------------------------------------------------------------------
__global__ __launch_bounds__(256) void cvt_kernel(
    const float* __restrict__ X,  const float* __restrict__ Wq,
    const float* __restrict__ Wk, const float* __restrict__ Wv,
    const int* __restrict__ mask,
    _Float16* __restrict__ Xh,  _Float16* __restrict__ Wqh,
    _Float16* __restrict__ Wkh, _Float16* __restrict__ Wvh,
    float* __restrict__ maskF)
{
    const int blk = blockIdx.x;
    if (blk >= 3584) {                       // mask: 2 blocks x 2048 elements
        const int loc = blk - 3584;
        const size_t e = ((size_t)loc * 256 + threadIdx.x) * 8;
        #pragma unroll
        for (int i = 0; i < 8; ++i)
            maskF[e + i] = mask[e + i] ? EXP2_OFF : -1.0e30f;
        return;
    }
    const float* src; _Float16* dst; int loc;
    if (blk < 2048)      { src = X;  dst = Xh;  loc = blk; }
    else if (blk < 2560) { src = Wq; dst = Wqh; loc = blk - 2048; }
    else if (blk < 3072) { src = Wk; dst = Wkh; loc = blk - 2560; }
    else                 { src = Wv; dst = Wvh; loc = blk - 3072; }
    const size_t e = ((size_t)loc * 256 + threadIdx.x) * 8;
    float4 a = *reinterpret_cast<const float4*>(&src[e]);
    float4 b = *reinterpret_cast<const float4*>(&src[e + 4]);
    half8 h = { (_Float16)a.x, (_Float16)a.y, (_Float16)a.z, (_Float16)a.w,
                (_Float16)b.x, (_Float16)b.y, (_Float16)b.z, (_Float16)b.w };
    *reinterpret_cast<half8*>(&dst[e]) = h;
}

// ---------------------------------------------------------------------------
__device__ __forceinline__ void async_cp16(_Float16* lds, const _Float16* g) {
    __builtin_amdgcn_global_load_lds(
        (const __attribute__((address_space(1))) void*)g,
        (__attribute__((address_space(3))) void*)lds, 16, 0, 0);
}
__device__ __forceinline__ void async_cp4(float* lds, const float* g) {
    __builtin_amdgcn_global_load_lds(
        (const __attribute__((address_space(1))) void*)g,
        (__attribute__((address_space(3))) void*)lds, 4, 0, 0);
}

// v_permlane32_swap_b32: swaps lanes[32:63] of x with lanes[0:31] of y.
// NOTE: each executed permlane shows up as 8 cycles in SQ_LDS_BANK_CONFLICT
// (crossbar artifact) — the constant 4.19M there is NOT ds_read contention.
__device__ __forceinline__ void permlane32_swap(unsigned &x, unsigned &y) {
    asm("v_permlane32_swap_b32 %0, %1" : "+v"(x), "+v"(y));
}

// ---------------------------------------------------------------------------
// Kernel A: QKV projection.  Counted-vmcnt 3-buffer pipeline (kept from r8).
// ---------------------------------------------------------------------------
__global__ __launch_bounds__(256) void qkv_proj_kernel(
    const _Float16* __restrict__ Xh,
    const _Float16* __restrict__ Wqh, const _Float16* __restrict__ Wkh,
    const _Float16* __restrict__ Wvh,
    const float* __restrict__ bq, const float* __restrict__ bk,
    const float* __restrict__ bv,
    _Float16* __restrict__ Qo, _Float16* __restrict__ Ko,
    _Float16* __restrict__ Vt)
{
    const int mode = blockIdx.z;
    const _Float16* W    = (mode == 0) ? Wqh : (mode == 1) ? Wkh : Wvh;
    const float*    bias = (mode == 0) ? bq  : (mode == 1) ? bk  : bv;

    const int m0 = blockIdx.x * 128, n0 = blockIdx.y * 128;
    const int tid = threadIdx.x, wave = tid >> 6, lane = tid & 63;
    const int l31 = lane & 31, kg = lane >> 5;      // kg: k-half group (0/1)

    __shared__ _Float16 SMEM[24576];   // 48 KB: 3 bufs x (As 4096 | Bs 4096)

    f32x16 acc[2][2];
    #pragma unroll
    for (int mt = 0; mt < 2; ++mt)
        #pragma unroll
        for (int nt = 0; nt < 2; ++nt)
            #pragma unroll
            for (int i = 0; i < 16; ++i) acc[mt][nt][i] = 0.f;

    const int wm = (wave & 1) * 64, wn = (wave >> 1) * 64;

    const int srow = tid >> 2, spos = tid & 3;
    auto stage = [&](int k0, int b) {
        _Float16* Asb = SMEM + b * 8192;
        _Float16* Bsb = Asb + 4096;
        #pragma unroll
        for (int j = 0; j < 2; ++j) {
            const int row = srow + j * 64;
            const int sch = spos ^ (row & 3);
            async_cp16(&Asb[j * 2048 + tid * 8],
                       &Xh[(size_t)(m0 + row) * HID + k0 + sch * 8]);
            async_cp16(&Bsb[j * 2048 + tid * 8],
                       &W [(size_t)(n0 + row) * HID + k0 + sch * 8]);
        }
    };

    constexpr int NIT = HID / 32;       // 32 iterations
    stage(0, 0);
    stage(32, 1);
    int buf = 0;

    for (int it = 0; it < NIT; ++it) {
        asm volatile("s_waitcnt vmcnt(4)" ::: "memory");
        __builtin_amdgcn_s_barrier();
        asm volatile("" ::: "memory");

        {   // prefetch tile it+2 (wrap refetch at the tail: harmless)
            int it2 = it + 2; if (it2 >= NIT) it2 -= NIT;
            int nb  = buf + 2; if (nb >= 3) nb -= 3;
            stage(it2 * 32, nb);
        }

        _Float16* Asb = SMEM + buf * 8192;
        _Float16* Bsb = Asb + 4096;

        #pragma unroll
        for (int c = 0; c < 2; ++c) {               // two k-16 chunks
            const int k8 = c * 2 + kg;              // 16B chunk idx (0..3)
            half8 af[2], bf[2];
            #pragma unroll
            for (int mt = 0; mt < 2; ++mt) {
                const int row = wm + mt * 32 + l31;
                af[mt] = *reinterpret_cast<const half8*>(
                    &Asb[row * 32 + ((k8 ^ (row & 3)) * 8)]);
            }
            #pragma unroll
            for (int nt = 0; nt < 2; ++nt) {
                const int row = wn + nt * 32 + l31;
                bf[nt] = *reinterpret_cast<const half8*>(
                    &Bsb[row * 32 + ((k8 ^ (row & 3)) * 8)]);
            }
            __builtin_amdgcn_s_setprio(1);
            #pragma unroll
            for (int mt = 0; mt < 2; ++mt)
                #pragma unroll
                for (int nt = 0; nt < 2; ++nt)
                    acc[mt][nt] = __builtin_amdgcn_mfma_f32_32x32x16_f16(
                        af[mt], bf[nt], acc[mt][nt], 0, 0, 0);
            __builtin_amdgcn_s_setprio(0);
        }
        if (++buf == 3) buf = 0;
    }
    // wrapped refetch DMAs must land before SMEM is reused as T
    asm volatile("s_waitcnt vmcnt(0)" ::: "memory");
    __syncthreads();

    _Float16* T = SMEM + wave * 4608;      // wave-private [64][72]

    const int nn  = n0 + wn;               // 64-aligned -> single head
    const int hh  = nn >> 6;
    const int mm  = m0 + wm;               // 64-aligned -> single batch
    const int bb  = mm >> 11;
    const int bhv = bb * HEADS + hh;
    const int s0  = mm & 2047;
    const int rowg = lane >> 3, chunk = lane & 7;   // store-phase mapping

    if (mode < 2) {
        _Float16* Out = (mode == 0) ? Qo : Ko;
        #pragma unroll
        for (int nt = 0; nt < 2; ++nt) {
            const int col = nt * 32 + l31;
            float bias_n = bias[nn + col];
            #pragma unroll
            for (int mt = 0; mt < 2; ++mt)
                #pragma unroll
                for (int r = 0; r < 16; ++r) {
                    const int row_l = (r & 3) + 8 * (r >> 2) + 4 * kg;
                    float v = acc[mt][nt][r] + bias_n;
                    if (mode == 0) v *= Q_SCALE;
                    T[(mt * 32 + row_l) * 72 + col] = (_Float16)v;
                }
        }
        asm volatile("s_waitcnt lgkmcnt(0)" ::: "memory");   // wave-private
        #pragma unroll
        for (int j = 0; j < 8; ++j) {
            const int sr = j * 8 + rowg;
            half8 v = *reinterpret_cast<const half8*>(&T[sr * 72 + chunk * 8]);
            *reinterpret_cast<half8*>(
                &Out[((size_t)bhv * S_LEN + s0 + sr) * HDIM + chunk * 8]) = v;
        }
    } else {
        #pragma unroll
        for (int nt = 0; nt < 2; ++nt) {
            const int col = nt * 32 + l31;
            const float bias_n = bias[nn + col];
            #pragma unroll
            for (int mt = 0; mt < 2; ++mt)
                #pragma unroll
                for (int rg = 0; rg < 4; ++rg) {
                    half4v t = { (_Float16)(acc[mt][nt][rg * 4 + 0] + bias_n),
                                 (_Float16)(acc[mt][nt][rg * 4 + 1] + bias_n),
                                 (_Float16)(acc[mt][nt][rg * 4 + 2] + bias_n),
                                 (_Float16)(acc[mt][nt][rg * 4 + 3] + bias_n) };
                    const int s_off = mt * 32 + 8 * rg + 4 * kg;
                    *reinterpret_cast<half4v*>(&T[col * 72 + s_off]) = t;
                }
        }
        asm volatile("s_waitcnt lgkmcnt(0)" ::: "memory");   // wave-private
        #pragma unroll
        for (int j = 0; j < 8; ++j) {
            const int dr = j * 8 + rowg;
            half8 v = *reinterpret_cast<const half8*>(&T[dr * 72 + chunk * 8]);
            *reinterpret_cast<half8*>(
                &Vt[((size_t)bhv * HDIM + dr) * S_LEN + s0 + chunk * 8]) = v;
        }
    }
}

// ---------------------------------------------------------------------------
// Kernel B: attention = r9 structure + T15 cross-tile software pipeline.
//   Pipes measured r9: MFMA 27.5% + LDS ~32% + VALU 41% ~= 100% of wall ->
//   barrier-lockstep serializes the bursts (all waves in the same phase).
//   Fix: per iteration issue QK(t) MFMAs FIRST, then run exp/pack/PV of
//   tile t-1 (state in registers: scP + vfP) while QK(t) occupies the
//   matrix pipe.  V-frags are prefetched to regs during their own tile's
//   iteration (all LDS reads of a buffer stay barrier-separated from the
//   stage that overwrites it -> race-free).  3-buf staging, vmcnt(3),
//   peeled first iter, register epilogue.
// ---------------------------------------------------------------------------
__global__ __launch_bounds__(512, 4) void attn_kernel(
    const _Float16* __restrict__ Q, const _Float16* __restrict__ K,
    const _Float16* __restrict__ Vt, const float* __restrict__ maskF,
    float* __restrict__ Out)
{
    const int id   = blockIdx.x;                    // 0..511
    const int xcd  = id & 7;
    const int bh   = xcd * 4 + ((id >> 3) & 3);     // 4 bh per XCD
    const int qt   = id >> 5;                       // 0..15
    const int b = bh >> 4, h = bh & 15;
    const int tid = threadIdx.x, wave = tid >> 6, lane = tid & 63;
    const int l31 = lane & 31, kg = lane >> 5;
    const int wq = wave & 3, wk = wave >> 2;

    __shared__ _Float16 SMEM[3 * 8192];   // 48 KB: 3 bufs x (K 64x64 | V 64x64)
    __shared__ float    Ms[3][8][64];     // 6 KB wave-private mask tiles

    const _Float16* Qb = Q  + (size_t)bh * S_LEN * HDIM;
    const _Float16* Kb = K  + (size_t)bh * S_LEN * HDIM;
    const _Float16* Vb = Vt + (size_t)bh * HDIM * S_LEN;
    const float*    mb = maskF + b * S_LEN;

    const int qrow = qt * 128 + wq * 32 + l31;

    half8 qf[4];
    #pragma unroll
    for (int kc = 0; kc < 4; ++kc)
        qf[kc] = *reinterpret_cast<const half8*>(
            &Qb[(size_t)qrow * HDIM + kc * 16 + kg * 8]);
    // retire qf BEFORE any staging so the DMA queue count stays clean
    asm volatile("s_waitcnt vmcnt(0)" ::: "memory");

    f32x16 acc[2];
    #pragma unroll
    for (int dt = 0; dt < 2; ++dt)
        #pragma unroll
        for (int i = 0; i < 16; ++i) acc[dt][i] = 0.f;
    float den = 0.f;

    // staging: 512 threads cover a full 64x64 tile per array: 1 cp16 each.
    // Per wave exactly 3 VMEM instrs/stage: K cp16 + V cp16 + mask cp4.
    const int srow = tid >> 3;                            // 0..63
    const int slot = tid & 7;
    const int gs   = (srow + (srow >> 3)) & 7;
    auto stage = [&](int tile, int bufsel) {
        const int kb   = tile * 64;
        const int csrc = slot ^ gs;
        _Float16* Kd = SMEM + bufsel * 8192;
        async_cp16(&Kd[tid * 8], &Kb[(size_t)(kb + srow) * HDIM + csrc * 8]);
        async_cp16(&Kd[4096 + tid * 8],
                   &Vb[(size_t)srow * S_LEN + kb + csrc * 8]);
        async_cp4(&Ms[bufsel][wave][lane], &mb[kb + lane]);
    };

    constexpr int NT = S_LEN / 64;        // 32 tiles
    // read-side swizzle keys
    const int gkey = (l31 + (l31 >> 3) + 4 * wk) & 7;
    const int gv0  = (l31 + (l31 >> 3)) & 7;
    const int gv1  = (gv0 + 4) & 7;

    // ---- per-tile QK + V-prefetch (all LDS reads of buf inside its iter) --
    auto qk_tile = [&](int bufsel, f32x16& scOut, half8 (&vfOut)[2][2]) {
        const _Float16* Kl = SMEM + bufsel * 8192;
        const _Float16* Vl = Kl + 4096;
        const float*    Mw = Ms[bufsel][wave];

        float4 mm0 = *reinterpret_cast<const float4*>(&Mw[wk * 32 + 0 + kg * 4]);
        float4 mm1 = *reinterpret_cast<const float4*>(&Mw[wk * 32 + 8 + kg * 4]);
        float4 mm2 = *reinterpret_cast<const float4*>(&Mw[wk * 32 + 16 + kg * 4]);
        float4 mm3 = *reinterpret_cast<const float4*>(&Mw[wk * 32 + 24 + kg * 4]);
        scOut = (f32x16){ mm0.x, mm0.y, mm0.z, mm0.w,
                          mm1.x, mm1.y, mm1.z, mm1.w,
                          mm2.x, mm2.y, mm2.z, mm2.w,
                          mm3.x, mm3.y, mm3.z, mm3.w };

        const _Float16* Krow = &Kl[(wk * 32 + l31) * 64];
        half8 kf[4];
        #pragma unroll
        for (int kc = 0; kc < 4; ++kc)
            kf[kc] = *reinterpret_cast<const half8*>(
                &Krow[((kc * 2 + kg) ^ gkey) * 8]);
        __builtin_amdgcn_s_setprio(1);
        #pragma unroll
        for (int kc = 0; kc < 4; ++kc)
            scOut = __builtin_amdgcn_mfma_f32_32x32x16_f16(
                kf[kc], qf[kc], scOut, 0, 0, 0);
        __builtin_amdgcn_s_setprio(0);

        #pragma unroll
        for (int dt = 0; dt < 2; ++dt) {
            const _Float16* Vrow = &Vl[(dt * 32 + l31) * 64];
            const int gv = dt ? gv1 : gv0;
            #pragma unroll
            for (int hh = 0; hh < 2; ++hh)
                vfOut[dt][hh] = *reinterpret_cast<const half8*>(
                    &Vrow[((wk * 4 + hh * 2 + kg) ^ gv) * 8]);
        }
    };

    // ---- finish previous tile: exp -> den -> pack -> PV (registers only) --
    auto finish_tile = [&](const f32x16& scP, const half8 (&vfP)[2][2]) {
        float p[16];
        #pragma unroll
        for (int r = 0; r < 16; ++r)
            p[r] = __builtin_amdgcn_exp2f(scP[r]);
        den += (((p[0] + p[1]) + (p[2] + p[3])) +
                ((p[4] + p[5]) + (p[6] + p[7]))) +
               (((p[8] + p[9]) + (p[10] + p[11])) +
                ((p[12] + p[13]) + (p[14] + p[15])));

        #pragma unroll
        for (int hh = 0; hh < 2; ++hh) {
            unsigned a0 = __builtin_bit_cast(unsigned,
                __builtin_amdgcn_cvt_pkrtz(p[hh * 8 + 0], p[hh * 8 + 1]));
            unsigned a1 = __builtin_bit_cast(unsigned,
                __builtin_amdgcn_cvt_pkrtz(p[hh * 8 + 2], p[hh * 8 + 3]));
            unsigned b0 = __builtin_bit_cast(unsigned,
                __builtin_amdgcn_cvt_pkrtz(p[hh * 8 + 4], p[hh * 8 + 5]));
            unsigned b1 = __builtin_bit_cast(unsigned,
                __builtin_amdgcn_cvt_pkrtz(p[hh * 8 + 6], p[hh * 8 + 7]));
            permlane32_swap(a0, b0);   // a0 = d0, b0 = d2
            permlane32_swap(a1, b1);   // a1 = d1, b1 = d3
            uint4v pd = { a0, a1, b0, b1 };
            half8 pf = __builtin_bit_cast(half8, pd);
            __builtin_amdgcn_s_setprio(1);
            acc[0] = __builtin_amdgcn_mfma_f32_32x32x16_f16(
                vfP[0][hh], pf, acc[0], 0, 0, 0);
            acc[1] = __builtin_amdgcn_mfma_f32_32x32x16_f16(
                vfP[1][hh], pf, acc[1], 0, 0, 0);
            __builtin_amdgcn_s_setprio(0);
        }
    };

    stage(0, 0);
    stage(1, 1);

    // ---- peeled iter 0: QK(0) only ----
    f32x16 scP;
    half8  vfP[2][2];
    asm volatile("s_waitcnt vmcnt(3)" ::: "memory");
    __builtin_amdgcn_s_barrier();
    asm volatile("" ::: "memory");
    stage(2, 2);
    qk_tile(0, scP, vfP);

    for (int t = 1; t < NT; ++t) {
        asm volatile("s_waitcnt vmcnt(3)" ::: "memory");
        __builtin_amdgcn_s_barrier();
        asm volatile("" ::: "memory");

        {   // prefetch tile t+2 into buf (t+2)%3 (tile t-1's buffer; all its
            // reads happened in iter t-1, barrier-separated -> safe)
            int nt2 = t + 2; if (nt2 >= NT) nt2 -= NT;
            int nb  = t + 2; nb -= (nb / 3) * 3;
            stage(nt2, nb);
        }

        f32x16 scC;
        half8  vfC[2][2];
        qk_tile(t - (t / 3) * 3, scC, vfC);   // issue QK(t) MFMAs first
        finish_tile(scP, vfP);                 // VALU overlaps matrix pipe

        scP = scC;
        #pragma unroll
        for (int dt = 0; dt < 2; ++dt)
            #pragma unroll
            for (int hh = 0; hh < 2; ++hh)
                vfP[dt][hh] = vfC[dt][hh];
    }
    finish_tile(scP, vfP);                     // epilogue: tile NT-1

    // ---- combine the two key-halves through dead staging LDS ----
    asm volatile("s_waitcnt vmcnt(0)" ::: "memory");   // tail DMAs landed
    __syncthreads();

    den += __shfl_xor(den, 32, 64);     // combine kg halves (both hold q=l31)

    float* LF = reinterpret_cast<float*>(SMEM);        // 12288 floats avail
    float* DF = reinterpret_cast<float*>(Ms);
    if (wk == 1) {
        float* wbase = LF + (wq * 64 + lane) * 36;     // pad 36: bank spread
        #pragma unroll
        for (int dt = 0; dt < 2; ++dt)
            #pragma unroll
            for (int g = 0; g < 4; ++g) {
                float4 o = { acc[dt][g * 4 + 0], acc[dt][g * 4 + 1],
                             acc[dt][g * 4 + 2], acc[dt][g * 4 + 3] };
                *reinterpret_cast<float4*>(&wbase[dt * 16 + g * 4]) = o;
            }
        if (kg == 0) DF[wq * 32 + l31] = den;
    }
    __syncthreads();
    if (wk == 0) {
        const float* rbase = LF + (wq * 64 + lane) * 36;
        const float inv = 1.0f / (den + DF[wq * 32 + l31]);
        float* orow = Out + ((size_t)(b * S_LEN + qrow)) * HID + h * HDIM;
        #pragma unroll
        for (int dt = 0; dt < 2; ++dt)
            #pragma unroll
            for (int g = 0; g < 4; ++g) {
                float4 pv = *reinterpret_cast<const float4*>(
                    &rbase[dt * 16 + g * 4]);
                float4 o = { (acc[dt][g * 4 + 0] + pv.x) * inv,
                             (acc[dt][g * 4 + 1] + pv.y) * inv,
                             (acc[dt][g * 4 + 2] + pv.z) * inv,
                             (acc[dt][g * 4 + 3] + pv.w) * inv };
                *reinterpret_cast<float4*>(&orow[dt * 32 + g * 8 + kg * 4]) = o;
            }
    }
}

// ---------------------------------------------------------------------------
extern "C" void kernel_launch(void* const* d_in, const int* in_sizes, int n_in,
                              void* d_out, int out_size, void* d_ws, size_t ws_size,
                              hipStream_t stream) {
    const float* X  = (const float*)d_in[0];
    const int*   mk = (const int*)  d_in[1];
    const float* Wq = (const float*)d_in[2];
    const float* bq = (const float*)d_in[3];
    const float* Wk = (const float*)d_in[4];
    const float* bk = (const float*)d_in[5];
    const float* Wv = (const float*)d_in[6];
    const float* bv = (const float*)d_in[7];
    float* out = (float*)d_out;

    // ws (halves): [Xh 4M][Wqh 1M][Wkh 1M][Wvh 1M][Q 4M][K 4M][Vt 4M][maskF]
    _Float16* Xh  = (_Float16*)d_ws;
    _Float16* Wqh = Xh  + (size_t)M_ROWS * HID;
    _Float16* Wkh = Wqh + (size_t)HID * HID;
    _Float16* Wvh = Wkh + (size_t)HID * HID;
    _Float16* Q   = Wvh + (size_t)HID * HID;
    _Float16* K   = Q   + (size_t)BH * S_LEN * HDIM;
    _Float16* Vt  = K   + (size_t)BH * S_LEN * HDIM;
    float*    maskF = (float*)(Vt + (size_t)BH * S_LEN * HDIM);

    cvt_kernel<<<3586, 256, 0, stream>>>(X, Wq, Wk, Wv, mk, Xh, Wqh, Wkh, Wvh, maskF);

    dim3 gp(M_ROWS / 128, HID / 128, 3);
    qkv_proj_kernel<<<gp, 256, 0, stream>>>(Xh, Wqh, Wkh, Wvh, bq, bk, bv, Q, K, Vt);

    attn_kernel<<<512, 512, 0, stream>>>(Q, K, Vt, maskF, out);
}

// Round 12
// 171.792 us; speedup vs baseline: 1.4135x; 1.4135x over previous
//
#include <hip/hip_runtime.h>
#include <hip/hip_fp16.h>

constexpr int S_LEN  = 2048;
constexpr int HID    = 1024;
constexpr int HEADS  = 16;
constexpr int HDIM   = 64;
constexpr int BATCH  = 2;
constexpr int BH     = BATCH * HEADS;          // 32
constexpr int M_ROWS = BATCH * S_LEN;          // 4096

typedef _Float16 half8  __attribute__((ext_vector_type(8)));
typedef _Float16 half4v __attribute__((ext_vector_type(4)));
typedef _Float16 half2v __attribute__((ext_vector_type(2)));
typedef float    f32x4  __attribute__((ext_vector_type(4)));
typedef float    f32x16 __attribute__((ext_vector_type(16)));
typedef unsigned uint4v __attribute__((ext_vector_type(4)));

constexpr float EXP2_OFF = -11.541560327111707f;   // -8*log2(e)
constexpr float Q_SCALE  = 0.18033688011112042f;   // 0.125*log2(e)

// ---------------------------------------------------------------------------
// Kernel 0: fp32 -> fp16 convert for X, Wq, Wk, Wv; mask -> fp32 exp2-bias.
// ---------------------------------------------------------------------------
__global__ __launch_bounds__(256) void cvt_kernel(
    const float* __restrict__ X,  const float* __restrict__ Wq,
    const float* __restrict__ Wk, const float* __restrict__ Wv,
    const int* __restrict__ mask,
    _Float16* __restrict__ Xh,  _Float16* __restrict__ Wqh,
    _Float16* __restrict__ Wkh, _Float16* __restrict__ Wvh,
    float* __restrict__ maskF)
{
    const int blk = blockIdx.x;
    if (blk >= 3584) {                       // mask: 2 blocks x 2048 elements
        const int loc = blk - 3584;
        const size_t e = ((size_t)loc * 256 + threadIdx.x) * 8;
        #pragma unroll
        for (int i = 0; i < 8; ++i)
            maskF[e + i] = mask[e + i] ? EXP2_OFF : -1.0e30f;
        return;
    }
    const float* src; _Float16* dst; int loc;
    if (blk < 2048)      { src = X;  dst = Xh;  loc = blk; }
    else if (blk < 2560) { src = Wq; dst = Wqh; loc = blk - 2048; }
    else if (blk < 3072) { src = Wk; dst = Wkh; loc = blk - 2560; }
    else                 { src = Wv; dst = Wvh; loc = blk - 3072; }
    const size_t e = ((size_t)loc * 256 + threadIdx.x) * 8;
    float4 a = *reinterpret_cast<const float4*>(&src[e]);
    float4 b = *reinterpret_cast<const float4*>(&src[e + 4]);
    half8 h = { (_Float16)a.x, (_Float16)a.y, (_Float16)a.z, (_Float16)a.w,
                (_Float16)b.x, (_Float16)b.y, (_Float16)b.z, (_Float16)b.w };
    *reinterpret_cast<half8*>(&dst[e]) = h;
}

// ---------------------------------------------------------------------------
__device__ __forceinline__ void async_cp16(_Float16* lds, const _Float16* g) {
    __builtin_amdgcn_global_load_lds(
        (const __attribute__((address_space(1))) void*)g,
        (__attribute__((address_space(3))) void*)lds, 16, 0, 0);
}
__device__ __forceinline__ void async_cp4(float* lds, const float* g) {
    __builtin_amdgcn_global_load_lds(
        (const __attribute__((address_space(1))) void*)g,
        (__attribute__((address_space(3))) void*)lds, 4, 0, 0);
}

// v_permlane32_swap_b32: swaps lanes[32:63] of x with lanes[0:31] of y.
// NOTE: each executed permlane shows up as 8 cycles in SQ_LDS_BANK_CONFLICT
// (crossbar artifact) — the constant 4.19M there is NOT ds_read contention.
__device__ __forceinline__ void permlane32_swap(unsigned &x, unsigned &y) {
    asm("v_permlane32_swap_b32 %0, %1" : "+v"(x), "+v"(y));
}

// ---------------------------------------------------------------------------
// Kernel A: QKV projection.  Counted-vmcnt 3-buffer pipeline (verified r8/r9:
//   raw s_barrier + vmcnt(4); staging DMAs stay in flight across the barrier).
//   Runtime buffer rotation kept deliberately — the x3-unrolled literal-index
//   variant (r11) miscompiled (absmax 0.157).  48 KB LDS.
// ---------------------------------------------------------------------------
__global__ __launch_bounds__(256) void qkv_proj_kernel(
    const _Float16* __restrict__ Xh,
    const _Float16* __restrict__ Wqh, const _Float16* __restrict__ Wkh,
    const _Float16* __restrict__ Wvh,
    const float* __restrict__ bq, const float* __restrict__ bk,
    const float* __restrict__ bv,
    _Float16* __restrict__ Qo, _Float16* __restrict__ Ko,
    _Float16* __restrict__ Vt)
{
    const int mode = blockIdx.z;
    const _Float16* W    = (mode == 0) ? Wqh : (mode == 1) ? Wkh : Wvh;
    const float*    bias = (mode == 0) ? bq  : (mode == 1) ? bk  : bv;

    const int m0 = blockIdx.x * 128, n0 = blockIdx.y * 128;
    const int tid = threadIdx.x, wave = tid >> 6, lane = tid & 63;
    const int l31 = lane & 31, kg = lane >> 5;      // kg: k-half group (0/1)

    __shared__ _Float16 SMEM[24576];   // 48 KB: 3 bufs x (As 4096 | Bs 4096)

    f32x16 acc[2][2];
    #pragma unroll
    for (int mt = 0; mt < 2; ++mt)
        #pragma unroll
        for (int nt = 0; nt < 2; ++nt)
            #pragma unroll
            for (int i = 0; i < 16; ++i) acc[mt][nt][i] = 0.f;

    const int wm = (wave & 1) * 64, wn = (wave >> 1) * 64;

    const int srow = tid >> 2, spos = tid & 3;
    auto stage = [&](int k0, int b) {
        _Float16* Asb = SMEM + b * 8192;
        _Float16* Bsb = Asb + 4096;
        #pragma unroll
        for (int j = 0; j < 2; ++j) {
            const int row = srow + j * 64;
            const int sch = spos ^ (row & 3);
            async_cp16(&Asb[j * 2048 + tid * 8],
                       &Xh[(size_t)(m0 + row) * HID + k0 + sch * 8]);
            async_cp16(&Bsb[j * 2048 + tid * 8],
                       &W [(size_t)(n0 + row) * HID + k0 + sch * 8]);
        }
    };

    constexpr int NIT = HID / 32;       // 32 iterations
    stage(0, 0);
    stage(32, 1);
    int buf = 0;

    for (int it = 0; it < NIT; ++it) {
        asm volatile("s_waitcnt vmcnt(4)" ::: "memory");
        __builtin_amdgcn_s_barrier();
        asm volatile("" ::: "memory");

        {   // prefetch tile it+2 (wrap refetch at the tail: harmless)
            int it2 = it + 2; if (it2 >= NIT) it2 -= NIT;
            int nb  = buf + 2; if (nb >= 3) nb -= 3;
            stage(it2 * 32, nb);
        }

        _Float16* Asb = SMEM + buf * 8192;
        _Float16* Bsb = Asb + 4096;

        #pragma unroll
        for (int c = 0; c < 2; ++c) {               // two k-16 chunks
            const int k8 = c * 2 + kg;              // 16B chunk idx (0..3)
            half8 af[2], bf[2];
            #pragma unroll
            for (int mt = 0; mt < 2; ++mt) {
                const int row = wm + mt * 32 + l31;
                af[mt] = *reinterpret_cast<const half8*>(
                    &Asb[row * 32 + ((k8 ^ (row & 3)) * 8)]);
            }
            #pragma unroll
            for (int nt = 0; nt < 2; ++nt) {
                const int row = wn + nt * 32 + l31;
                bf[nt] = *reinterpret_cast<const half8*>(
                    &Bsb[row * 32 + ((k8 ^ (row & 3)) * 8)]);
            }
            __builtin_amdgcn_s_setprio(1);
            #pragma unroll
            for (int mt = 0; mt < 2; ++mt)
                #pragma unroll
                for (int nt = 0; nt < 2; ++nt)
                    acc[mt][nt] = __builtin_amdgcn_mfma_f32_32x32x16_f16(
                        af[mt], bf[nt], acc[mt][nt], 0, 0, 0);
            __builtin_amdgcn_s_setprio(0);
        }
        if (++buf == 3) buf = 0;
    }
    // wrapped refetch DMAs must land before SMEM is reused as T
    asm volatile("s_waitcnt vmcnt(0)" ::: "memory");
    __syncthreads();

    _Float16* T = SMEM + wave * 4608;      // wave-private [64][72]

    const int nn  = n0 + wn;               // 64-aligned -> single head
    const int hh  = nn >> 6;
    const int mm  = m0 + wm;               // 64-aligned -> single batch
    const int bb  = mm >> 11;
    const int bhv = bb * HEADS + hh;
    const int s0  = mm & 2047;
    const int rowg = lane >> 3, chunk = lane & 7;   // store-phase mapping

    if (mode < 2) {
        _Float16* Out = (mode == 0) ? Qo : Ko;
        #pragma unroll
        for (int nt = 0; nt < 2; ++nt) {
            const int col = nt * 32 + l31;
            float bias_n = bias[nn + col];
            #pragma unroll
            for (int mt = 0; mt < 2; ++mt)
                #pragma unroll
                for (int r = 0; r < 16; ++r) {
                    const int row_l = (r & 3) + 8 * (r >> 2) + 4 * kg;
                    float v = acc[mt][nt][r] + bias_n;
                    if (mode == 0) v *= Q_SCALE;
                    T[(mt * 32 + row_l) * 72 + col] = (_Float16)v;
                }
        }
        asm volatile("s_waitcnt lgkmcnt(0)" ::: "memory");   // wave-private
        #pragma unroll
        for (int j = 0; j < 8; ++j) {
            const int sr = j * 8 + rowg;
            half8 v = *reinterpret_cast<const half8*>(&T[sr * 72 + chunk * 8]);
            *reinterpret_cast<half8*>(
                &Out[((size_t)bhv * S_LEN + s0 + sr) * HDIM + chunk * 8]) = v;
        }
    } else {
        #pragma unroll
        for (int nt = 0; nt < 2; ++nt) {
            const int col = nt * 32 + l31;
            const float bias_n = bias[nn + col];
            #pragma unroll
            for (int mt = 0; mt < 2; ++mt)
                #pragma unroll
                for (int rg = 0; rg < 4; ++rg) {
                    half4v t = { (_Float16)(acc[mt][nt][rg * 4 + 0] + bias_n),
                                 (_Float16)(acc[mt][nt][rg * 4 + 1] + bias_n),
                                 (_Float16)(acc[mt][nt][rg * 4 + 2] + bias_n),
                                 (_Float16)(acc[mt][nt][rg * 4 + 3] + bias_n) };
                    const int s_off = mt * 32 + 8 * rg + 4 * kg;
                    *reinterpret_cast<half4v*>(&T[col * 72 + s_off]) = t;
                }
        }
        asm volatile("s_waitcnt lgkmcnt(0)" ::: "memory");   // wave-private
        #pragma unroll
        for (int j = 0; j < 8; ++j) {
            const int dr = j * 8 + rowg;
            half8 v = *reinterpret_cast<const half8*>(&T[dr * 72 + chunk * 8]);
            *reinterpret_cast<half8*>(
                &Vt[((size_t)bhv * HDIM + dr) * S_LEN + s0 + chunk * 8]) = v;
        }
    }
}

// ---------------------------------------------------------------------------
// Kernel B: attention = r6 structure EXACTLY (best measured: 51.8 us).
//   512 blocks x 512 thr, 8 waves (wq x wk in-block key-split), C-init =
//   mask bias from LDS, counted vmcnt(3) + raw s_barrier, 3-buf staging,
//   in-register P (cvt_pkrtz + permlane32_swap), setprio around MFMA.
//   Rejected by experiment: T15 reg-pipeline (r10: spill, 129 us),
//   mask-from-global (r8: +traffic, 58.8), literal-idx unroll (r11: wrong).
// ---------------------------------------------------------------------------
__global__ __launch_bounds__(512, 4) void attn_kernel(
    const _Float16* __restrict__ Q, const _Float16* __restrict__ K,
    const _Float16* __restrict__ Vt, const float* __restrict__ maskF,
    float* __restrict__ Out)
{
    const int id   = blockIdx.x;                    // 0..511
    const int xcd  = id & 7;
    const int bh   = xcd * 4 + ((id >> 3) & 3);     // 4 bh per XCD
    const int qt   = id >> 5;                       // 0..15
    const int b = bh >> 4, h = bh & 15;
    const int tid = threadIdx.x, wave = tid >> 6, lane = tid & 63;
    const int l31 = lane & 31, kg = lane >> 5;
    const int wq = wave & 3, wk = wave >> 2;

    __shared__ _Float16 SMEM[3 * 8192];   // 48 KB: 3 bufs x (K 64x64 | V 64x64)
    __shared__ float    Ms[3][8][64];     // 6 KB wave-private mask tiles

    const _Float16* Qb = Q  + (size_t)bh * S_LEN * HDIM;
    const _Float16* Kb = K  + (size_t)bh * S_LEN * HDIM;
    const _Float16* Vb = Vt + (size_t)bh * HDIM * S_LEN;
    const float*    mb = maskF + b * S_LEN;

    const int qrow = qt * 128 + wq * 32 + l31;

    half8 qf[4];
    #pragma unroll
    for (int kc = 0; kc < 4; ++kc)
        qf[kc] = *reinterpret_cast<const half8*>(
            &Qb[(size_t)qrow * HDIM + kc * 16 + kg * 8]);
    // retire qf BEFORE any staging so the DMA queue count stays clean
    asm volatile("s_waitcnt vmcnt(0)" ::: "memory");

    f32x16 acc[2];
    #pragma unroll
    for (int dt = 0; dt < 2; ++dt)
        #pragma unroll
        for (int i = 0; i < 16; ++i) acc[dt][i] = 0.f;
    float den = 0.f;

    // staging: 512 threads cover a full 64x64 tile per array: 1 cp16 each.
    // Per wave exactly 3 VMEM instrs/stage: K cp16 + V cp16 + mask cp4.
    const int srow = tid >> 3;                            // 0..63
    const int slot = tid & 7;
    auto stage = [&](int tile, int bufsel) {
        const int kb   = tile * 64;
        const int csrc = slot ^ (srow & 7);
        _Float16* Kd = SMEM + bufsel * 8192;
        async_cp16(&Kd[tid * 8], &Kb[(size_t)(kb + srow) * HDIM + csrc * 8]);
        async_cp16(&Kd[4096 + tid * 8],
                   &Vb[(size_t)srow * S_LEN + kb + csrc * 8]);
        async_cp4(&Ms[bufsel][wave][lane], &mb[kb + lane]);
    };

    constexpr int NT = S_LEN / 64;        // 32 tiles
    stage(0, 0);
    stage(1, 1);
    int buf = 0;
    const int rsw = l31 & 7;              // read-side swizzle key (row&7)

    for (int t = 0; t < NT; ++t) {
        // tile t's 3 loads retired; tile t+1's 3 stay in flight
        asm volatile("s_waitcnt vmcnt(3)" ::: "memory");
        __builtin_amdgcn_s_barrier();
        asm volatile("" ::: "memory");

        {   // prefetch tile t+2 (wraps at the tail: harmless refetch)
            int nt2 = t + 2; if (nt2 >= NT) nt2 -= NT;
            int nb  = buf + 2; if (nb >= 3) nb -= 3;
            stage(nt2, nb);
        }

        const _Float16* Kl = SMEM + buf * 8192;
        const _Float16* Vl = Kl + 4096;
        const float*    Mw = Ms[buf][wave];

        // ---- sc init = mask bias (C-operand), keys wk*32 + row_l(r) ----
        float4 mm0 = *reinterpret_cast<const float4*>(&Mw[wk * 32 + 0 + kg * 4]);
        float4 mm1 = *reinterpret_cast<const float4*>(&Mw[wk * 32 + 8 + kg * 4]);
        float4 mm2 = *reinterpret_cast<const float4*>(&Mw[wk * 32 + 16 + kg * 4]);
        float4 mm3 = *reinterpret_cast<const float4*>(&Mw[wk * 32 + 24 + kg * 4]);
        f32x16 sc = { mm0.x, mm0.y, mm0.z, mm0.w,
                      mm1.x, mm1.y, mm1.z, mm1.w,
                      mm2.x, mm2.y, mm2.z, mm2.w,
                      mm3.x, mm3.y, mm3.z, mm3.w };

        // ---- S^T = K.Q^T + bias : 4 chained 32x32x16 on this wave's keys --
        const _Float16* Krow = &Kl[(wk * 32 + l31) * 64];
        half8 kf[4];
        #pragma unroll
        for (int kc = 0; kc < 4; ++kc)
            kf[kc] = *reinterpret_cast<const half8*>(
                &Krow[((kc * 2 + kg) ^ rsw) * 8]);
        __builtin_amdgcn_s_setprio(1);
        #pragma unroll
        for (int kc = 0; kc < 4; ++kc)
            sc = __builtin_amdgcn_mfma_f32_32x32x16_f16(kf[kc], qf[kc], sc, 0, 0, 0);
        __builtin_amdgcn_s_setprio(0);

        // ---- V fragments: chunks of this wave's 32 keys ----
        half8 vf[2][2];
        #pragma unroll
        for (int dt = 0; dt < 2; ++dt) {
            const _Float16* Vrow = &Vl[(dt * 32 + l31) * 64];
            #pragma unroll
            for (int hh = 0; hh < 2; ++hh)
                vf[dt][hh] = *reinterpret_cast<const half8*>(
                    &Vrow[((wk * 4 + hh * 2 + kg) ^ rsw) * 8]);
        }

        // ---- p = 2^sc ; den ; in-register P^T frags ; PV ----
        float p[16];
        #pragma unroll
        for (int r = 0; r < 16; ++r)
            p[r] = __builtin_amdgcn_exp2f(sc[r]);
        den += (((p[0] + p[1]) + (p[2] + p[3])) +
                ((p[4] + p[5]) + (p[6] + p[7]))) +
               (((p[8] + p[9]) + (p[10] + p[11])) +
                ((p[12] + p[13]) + (p[14] + p[15])));

        #pragma unroll
        for (int hh = 0; hh < 2; ++hh) {
            unsigned a0 = __builtin_bit_cast(unsigned,
                __builtin_amdgcn_cvt_pkrtz(p[hh * 8 + 0], p[hh * 8 + 1]));
            unsigned a1 = __builtin_bit_cast(unsigned,
                __builtin_amdgcn_cvt_pkrtz(p[hh * 8 + 2], p[hh * 8 + 3]));
            unsigned b0 = __builtin_bit_cast(unsigned,
                __builtin_amdgcn_cvt_pkrtz(p[hh * 8 + 4], p[hh * 8 + 5]));
            unsigned b1 = __builtin_bit_cast(unsigned,
                __builtin_amdgcn_cvt_pkrtz(p[hh * 8 + 6], p[hh * 8 + 7]));
            permlane32_swap(a0, b0);   // a0 = d0, b0 = d2
            permlane32_swap(a1, b1);   // a1 = d1, b1 = d3
            uint4v pd = { a0, a1, b0, b1 };
            half8 pf = __builtin_bit_cast(half8, pd);
            __builtin_amdgcn_s_setprio(1);
            acc[0] = __builtin_amdgcn_mfma_f32_32x32x16_f16(
                vf[0][hh], pf, acc[0], 0, 0, 0);
            acc[1] = __builtin_amdgcn_mfma_f32_32x32x16_f16(
                vf[1][hh], pf, acc[1], 0, 0, 0);
            __builtin_amdgcn_s_setprio(0);
        }
        if (++buf == 3) buf = 0;
    }

    // ---- combine the two key-halves through dead staging LDS ----
    asm volatile("s_waitcnt vmcnt(0)" ::: "memory");   // tail DMAs landed
    __syncthreads();

    den += __shfl_xor(den, 32, 64);     // combine kg halves (both hold q=l31)

    float* LF = reinterpret_cast<float*>(SMEM);        // 12288 floats avail
    float* DF = reinterpret_cast<float*>(Ms);
    if (wk == 1) {
        float* wbase = LF + (wq * 64 + lane) * 36;     // pad 36: bank spread
        #pragma unroll
        for (int dt = 0; dt < 2; ++dt)
            #pragma unroll
            for (int g = 0; g < 4; ++g) {
                float4 o = { acc[dt][g * 4 + 0], acc[dt][g * 4 + 1],
                             acc[dt][g * 4 + 2], acc[dt][g * 4 + 3] };
                *reinterpret_cast<float4*>(&wbase[dt * 16 + g * 4]) = o;
            }
        if (kg == 0) DF[wq * 32 + l31] = den;
    }
    __syncthreads();
    if (wk == 0) {
        const float* rbase = LF + (wq * 64 + lane) * 36;
        const float inv = 1.0f / (den + DF[wq * 32 + l31]);
        float* orow = Out + ((size_t)(b * S_LEN + qrow)) * HID + h * HDIM;
        #pragma unroll
        for (int dt = 0; dt < 2; ++dt)
            #pragma unroll
            for (int g = 0; g < 4; ++g) {
                float4 pv = *reinterpret_cast<const float4*>(
                    &rbase[dt * 16 + g * 4]);
                float4 o = { (acc[dt][g * 4 + 0] + pv.x) * inv,
                             (acc[dt][g * 4 + 1] + pv.y) * inv,
                             (acc[dt][g * 4 + 2] + pv.z) * inv,
                             (acc[dt][g * 4 + 3] + pv.w) * inv };
                *reinterpret_cast<float4*>(&orow[dt * 32 + g * 8 + kg * 4]) = o;
            }
    }
}

// ---------------------------------------------------------------------------
extern "C" void kernel_launch(void* const* d_in, const int* in_sizes, int n_in,
                              void* d_out, int out_size, void* d_ws, size_t ws_size,
                              hipStream_t stream) {
    const float* X  = (const float*)d_in[0];
    const int*   mk = (const int*)  d_in[1];
    const float* Wq = (const float*)d_in[2];
    const float* bq = (const float*)d_in[3];
    const float* Wk = (const float*)d_in[4];
    const float* bk = (const float*)d_in[5];
    const float* Wv = (const float*)d_in[6];
    const float* bv = (const float*)d_in[7];
    float* out = (float*)d_out;

    // ws (halves): [Xh 4M][Wqh 1M][Wkh 1M][Wvh 1M][Q 4M][K 4M][Vt 4M][maskF]
    _Float16* Xh  = (_Float16*)d_ws;
    _Float16* Wqh = Xh  + (size_t)M_ROWS * HID;
    _Float16* Wkh = Wqh + (size_t)HID * HID;
    _Float16* Wvh = Wkh + (size_t)HID * HID;
    _Float16* Q   = Wvh + (size_t)HID * HID;
    _Float16* K   = Q   + (size_t)BH * S_LEN * HDIM;
    _Float16* Vt  = K   + (size_t)BH * S_LEN * HDIM;
    float*    maskF = (float*)(Vt + (size_t)BH * S_LEN * HDIM);

    cvt_kernel<<<3586, 256, 0, stream>>>(X, Wq, Wk, Wv, mk, Xh, Wqh, Wkh, Wvh, maskF);

    dim3 gp(M_ROWS / 128, HID / 128, 3);
    qkv_proj_kernel<<<gp, 256, 0, stream>>>(Xh, Wqh, Wkh, Wvh, bq, bk, bv, Q, K, Vt);

    attn_kernel<<<512, 512, 0, stream>>>(Q, K, Vt, maskF, out);
}

// Round 13
// 171.144 us; speedup vs baseline: 1.4188x; 1.0038x over previous
//
#include <hip/hip_runtime.h>
#include <hip/hip_fp16.h>

constexpr int S_LEN  = 2048;
constexpr int HID    = 1024;
constexpr int HEADS  = 16;
constexpr int HDIM   = 64;
constexpr int BATCH  = 2;
constexpr int BH     = BATCH * HEADS;          // 32
constexpr int M_ROWS = BATCH * S_LEN;          // 4096

typedef _Float16 half8  __attribute__((ext_vector_type(8)));
typedef _Float16 half4v __attribute__((ext_vector_type(4)));
typedef _Float16 half2v __attribute__((ext_vector_type(2)));
typedef float    f32x4  __attribute__((ext_vector_type(4)));
typedef float    f32x16 __attribute__((ext_vector_type(16)));
typedef unsigned uint4v __attribute__((ext_vector_type(4)));

constexpr float EXP2_OFF = -11.541560327111707f;   // -8*log2(e)
constexpr float Q_SCALE  = 0.18033688011112042f;   // 0.125*log2(e)

// ---------------------------------------------------------------------------
// Kernel 0: fp32 -> fp16 convert for X, Wq, Wk, Wv; mask -> fp32 exp2-bias.
// ---------------------------------------------------------------------------
__global__ __launch_bounds__(256) void cvt_kernel(
    const float* __restrict__ X,  const float* __restrict__ Wq,
    const float* __restrict__ Wk, const float* __restrict__ Wv,
    const int* __restrict__ mask,
    _Float16* __restrict__ Xh,  _Float16* __restrict__ Wqh,
    _Float16* __restrict__ Wkh, _Float16* __restrict__ Wvh,
    float* __restrict__ maskF)
{
    const int blk = blockIdx.x;
    if (blk >= 3584) {                       // mask: 2 blocks x 2048 elements
        const int loc = blk - 3584;
        const size_t e = ((size_t)loc * 256 + threadIdx.x) * 8;
        #pragma unroll
        for (int i = 0; i < 8; ++i)
            maskF[e + i] = mask[e + i] ? EXP2_OFF : -1.0e30f;
        return;
    }
    const float* src; _Float16* dst; int loc;
    if (blk < 2048)      { src = X;  dst = Xh;  loc = blk; }
    else if (blk < 2560) { src = Wq; dst = Wqh; loc = blk - 2048; }
    else if (blk < 3072) { src = Wk; dst = Wkh; loc = blk - 2560; }
    else                 { src = Wv; dst = Wvh; loc = blk - 3072; }
    const size_t e = ((size_t)loc * 256 + threadIdx.x) * 8;
    float4 a = *reinterpret_cast<const float4*>(&src[e]);
    float4 b = *reinterpret_cast<const float4*>(&src[e + 4]);
    half8 h = { (_Float16)a.x, (_Float16)a.y, (_Float16)a.z, (_Float16)a.w,
                (_Float16)b.x, (_Float16)b.y, (_Float16)b.z, (_Float16)b.w };
    *reinterpret_cast<half8*>(&dst[e]) = h;
}

// ---------------------------------------------------------------------------
__device__ __forceinline__ void async_cp16(_Float16* lds, const _Float16* g) {
    __builtin_amdgcn_global_load_lds(
        (const __attribute__((address_space(1))) void*)g,
        (__attribute__((address_space(3))) void*)lds, 16, 0, 0);
}
__device__ __forceinline__ void async_cp4(float* lds, const float* g) {
    __builtin_amdgcn_global_load_lds(
        (const __attribute__((address_space(1))) void*)g,
        (__attribute__((address_space(3))) void*)lds, 4, 0, 0);
}

// v_permlane32_swap_b32: swaps lanes[32:63] of x with lanes[0:31] of y.
// NOTE: each executed permlane shows up as 8 cycles in SQ_LDS_BANK_CONFLICT
// (crossbar artifact) — attn's constant 4.19M there is NOT ds_read contention.
__device__ __forceinline__ void permlane32_swap(unsigned &x, unsigned &y) {
    asm("v_permlane32_swap_b32 %0, %1" : "+v"(x), "+v"(y));
}

// ---------------------------------------------------------------------------
// Kernel A: QKV projection.  Counted-vmcnt 3-buffer pipeline (verified r8/r12)
//   + this round:
//   (1) conflict-free chunk swizzle g(row) = (row + (row>>2)) & 3.  The old
//       g=row&3 put lanes l, l+4, l+8, l+12 (same row&3; rows 256B apart ==
//       0 mod 128) on the SAME bank -> 8-way conflict on every b128 read
//       (the real 9.6M SQ_LDS_BANK_CONFLICT).  New g: those rows get
//       distinct slots; only l<->l+16 alias -> 2-way (free).
//   (2) XCD-aware 1D grid: each XCD owns 3 (n,mode) combos x all 32 m-tiles
//       -> each 256KB W-panel fetched once per XCD (was 8x; FETCH 33.9MB).
// ---------------------------------------------------------------------------
__global__ __launch_bounds__(256) void qkv_proj_kernel(
    const _Float16* __restrict__ Xh,
    const _Float16* __restrict__ Wqh, const _Float16* __restrict__ Wkh,
    const _Float16* __restrict__ Wvh,
    const float* __restrict__ bq, const float* __restrict__ bk,
    const float* __restrict__ bv,
    _Float16* __restrict__ Qo, _Float16* __restrict__ Ko,
    _Float16* __restrict__ Vt)
{
    // bijective decode: id -> (xcd 0..7, cidx 0..2, m 0..31); combo = n + 8*mode
    const int id    = blockIdx.x;            // 0..767
    const int xcd   = id & 7;
    const int local = id >> 3;               // 0..95
    const int combo = xcd * 3 + (local >> 5);// 0..23
    const int mtile = local & 31;
    const int nB    = combo & 7;
    const int mode  = combo >> 3;            // 0..2

    const _Float16* W    = (mode == 0) ? Wqh : (mode == 1) ? Wkh : Wvh;
    const float*    bias = (mode == 0) ? bq  : (mode == 1) ? bk  : bv;

    const int m0 = mtile * 128, n0 = nB * 128;
    const int tid = threadIdx.x, wave = tid >> 6, lane = tid & 63;
    const int l31 = lane & 31, kg = lane >> 5;      // kg: k-half group (0/1)

    __shared__ _Float16 SMEM[24576];   // 48 KB: 3 bufs x (As 4096 | Bs 4096)

    f32x16 acc[2][2];
    #pragma unroll
    for (int mt = 0; mt < 2; ++mt)
        #pragma unroll
        for (int nt = 0; nt < 2; ++nt)
            #pragma unroll
            for (int i = 0; i < 16; ++i) acc[mt][nt][i] = 0.f;

    const int wm = (wave & 1) * 64, wn = (wave >> 1) * 64;

    const int srow = tid >> 2, spos = tid & 3;
    auto stage = [&](int k0, int b) {
        _Float16* Asb = SMEM + b * 8192;
        _Float16* Bsb = Asb + 4096;
        #pragma unroll
        for (int j = 0; j < 2; ++j) {
            const int row = srow + j * 64;
            const int sch = spos ^ ((row + (row >> 2)) & 3);
            async_cp16(&Asb[j * 2048 + tid * 8],
                       &Xh[(size_t)(m0 + row) * HID + k0 + sch * 8]);
            async_cp16(&Bsb[j * 2048 + tid * 8],
                       &W [(size_t)(n0 + row) * HID + k0 + sch * 8]);
        }
    };

    constexpr int NIT = HID / 32;       // 32 iterations
    stage(0, 0);
    stage(32, 1);
    int buf = 0;

    for (int it = 0; it < NIT; ++it) {
        asm volatile("s_waitcnt vmcnt(4)" ::: "memory");
        __builtin_amdgcn_s_barrier();
        asm volatile("" ::: "memory");

        {   // prefetch tile it+2 (wrap refetch at the tail: harmless)
            int it2 = it + 2; if (it2 >= NIT) it2 -= NIT;
            int nb  = buf + 2; if (nb >= 3) nb -= 3;
            stage(it2 * 32, nb);
        }

        _Float16* Asb = SMEM + buf * 8192;
        _Float16* Bsb = Asb + 4096;

        #pragma unroll
        for (int c = 0; c < 2; ++c) {               // two k-16 chunks
            const int k8 = c * 2 + kg;              // 16B chunk idx (0..3)
            half8 af[2], bf[2];
            #pragma unroll
            for (int mt = 0; mt < 2; ++mt) {
                const int row = wm + mt * 32 + l31;
                const int g   = (row + (row >> 2)) & 3;
                af[mt] = *reinterpret_cast<const half8*>(
                    &Asb[row * 32 + ((k8 ^ g) * 8)]);
            }
            #pragma unroll
            for (int nt = 0; nt < 2; ++nt) {
                const int row = wn + nt * 32 + l31;
                const int g   = (row + (row >> 2)) & 3;
                bf[nt] = *reinterpret_cast<const half8*>(
                    &Bsb[row * 32 + ((k8 ^ g) * 8)]);
            }
            __builtin_amdgcn_s_setprio(1);
            #pragma unroll
            for (int mt = 0; mt < 2; ++mt)
                #pragma unroll
                for (int nt = 0; nt < 2; ++nt)
                    acc[mt][nt] = __builtin_amdgcn_mfma_f32_32x32x16_f16(
                        af[mt], bf[nt], acc[mt][nt], 0, 0, 0);
            __builtin_amdgcn_s_setprio(0);
        }
        if (++buf == 3) buf = 0;
    }
    // wrapped refetch DMAs must land before SMEM is reused as T
    asm volatile("s_waitcnt vmcnt(0)" ::: "memory");
    __syncthreads();

    _Float16* T = SMEM + wave * 4608;      // wave-private [64][72]

    const int nn  = n0 + wn;               // 64-aligned -> single head
    const int hh  = nn >> 6;
    const int mm  = m0 + wm;               // 64-aligned -> single batch
    const int bb  = mm >> 11;
    const int bhv = bb * HEADS + hh;
    const int s0  = mm & 2047;
    const int rowg = lane >> 3, chunk = lane & 7;   // store-phase mapping

    if (mode < 2) {
        _Float16* Out = (mode == 0) ? Qo : Ko;
        #pragma unroll
        for (int nt = 0; nt < 2; ++nt) {
            const int col = nt * 32 + l31;
            float bias_n = bias[nn + col];
            #pragma unroll
            for (int mt = 0; mt < 2; ++mt)
                #pragma unroll
                for (int r = 0; r < 16; ++r) {
                    const int row_l = (r & 3) + 8 * (r >> 2) + 4 * kg;
                    float v = acc[mt][nt][r] + bias_n;
                    if (mode == 0) v *= Q_SCALE;
                    T[(mt * 32 + row_l) * 72 + col] = (_Float16)v;
                }
        }
        asm volatile("s_waitcnt lgkmcnt(0)" ::: "memory");   // wave-private
        #pragma unroll
        for (int j = 0; j < 8; ++j) {
            const int sr = j * 8 + rowg;
            half8 v = *reinterpret_cast<const half8*>(&T[sr * 72 + chunk * 8]);
            *reinterpret_cast<half8*>(
                &Out[((size_t)bhv * S_LEN + s0 + sr) * HDIM + chunk * 8]) = v;
        }
    } else {
        #pragma unroll
        for (int nt = 0; nt < 2; ++nt) {
            const int col = nt * 32 + l31;
            const float bias_n = bias[nn + col];
            #pragma unroll
            for (int mt = 0; mt < 2; ++mt)
                #pragma unroll
                for (int rg = 0; rg < 4; ++rg) {
                    half4v t = { (_Float16)(acc[mt][nt][rg * 4 + 0] + bias_n),
                                 (_Float16)(acc[mt][nt][rg * 4 + 1] + bias_n),
                                 (_Float16)(acc[mt][nt][rg * 4 + 2] + bias_n),
                                 (_Float16)(acc[mt][nt][rg * 4 + 3] + bias_n) };
                    const int s_off = mt * 32 + 8 * rg + 4 * kg;
                    *reinterpret_cast<half4v*>(&T[col * 72 + s_off]) = t;
                }
        }
        asm volatile("s_waitcnt lgkmcnt(0)" ::: "memory");   // wave-private
        #pragma unroll
        for (int j = 0; j < 8; ++j) {
            const int dr = j * 8 + rowg;
            half8 v = *reinterpret_cast<const half8*>(&T[dr * 72 + chunk * 8]);
            *reinterpret_cast<half8*>(
                &Vt[((size_t)bhv * HDIM + dr) * S_LEN + s0 + chunk * 8]) = v;
        }
    }
}

// ---------------------------------------------------------------------------
// Kernel B: attention = r6/r12 structure EXACTLY (best measured: 50.4 us).
//   512 blocks x 512 thr, 8 waves (wq x wk in-block key-split), C-init =
//   mask bias from LDS, counted vmcnt(3) + raw s_barrier, 3-buf staging,
//   in-register P (cvt_pkrtz + permlane32_swap), setprio around MFMA.
//   Rejected by experiment: T15 reg-pipeline (r10: spill, 129 us),
//   mask-from-global (r8: +traffic), literal-idx unroll (r11: miscompile).
// ---------------------------------------------------------------------------
__global__ __launch_bounds__(512, 4) void attn_kernel(
    const _Float16* __restrict__ Q, const _Float16* __restrict__ K,
    const _Float16* __restrict__ Vt, const float* __restrict__ maskF,
    float* __restrict__ Out)
{
    const int id   = blockIdx.x;                    // 0..511
    const int xcd  = id & 7;
    const int bh   = xcd * 4 + ((id >> 3) & 3);     // 4 bh per XCD
    const int qt   = id >> 5;                       // 0..15
    const int b = bh >> 4, h = bh & 15;
    const int tid = threadIdx.x, wave = tid >> 6, lane = tid & 63;
    const int l31 = lane & 31, kg = lane >> 5;
    const int wq = wave & 3, wk = wave >> 2;

    __shared__ _Float16 SMEM[3 * 8192];   // 48 KB: 3 bufs x (K 64x64 | V 64x64)
    __shared__ float    Ms[3][8][64];     // 6 KB wave-private mask tiles

    const _Float16* Qb = Q  + (size_t)bh * S_LEN * HDIM;
    const _Float16* Kb = K  + (size_t)bh * S_LEN * HDIM;
    const _Float16* Vb = Vt + (size_t)bh * HDIM * S_LEN;
    const float*    mb = maskF + b * S_LEN;

    const int qrow = qt * 128 + wq * 32 + l31;

    half8 qf[4];
    #pragma unroll
    for (int kc = 0; kc < 4; ++kc)
        qf[kc] = *reinterpret_cast<const half8*>(
            &Qb[(size_t)qrow * HDIM + kc * 16 + kg * 8]);
    // retire qf BEFORE any staging so the DMA queue count stays clean
    asm volatile("s_waitcnt vmcnt(0)" ::: "memory");

    f32x16 acc[2];
    #pragma unroll
    for (int dt = 0; dt < 2; ++dt)
        #pragma unroll
        for (int i = 0; i < 16; ++i) acc[dt][i] = 0.f;
    float den = 0.f;

    // staging: 512 threads cover a full 64x64 tile per array: 1 cp16 each.
    // Per wave exactly 3 VMEM instrs/stage: K cp16 + V cp16 + mask cp4.
    const int srow = tid >> 3;                            // 0..63
    const int slot = tid & 7;
    auto stage = [&](int tile, int bufsel) {
        const int kb   = tile * 64;
        const int csrc = slot ^ (srow & 7);
        _Float16* Kd = SMEM + bufsel * 8192;
        async_cp16(&Kd[tid * 8], &Kb[(size_t)(kb + srow) * HDIM + csrc * 8]);
        async_cp16(&Kd[4096 + tid * 8],
                   &Vb[(size_t)srow * S_LEN + kb + csrc * 8]);
        async_cp4(&Ms[bufsel][wave][lane], &mb[kb + lane]);
    };

    constexpr int NT = S_LEN / 64;        // 32 tiles
    stage(0, 0);
    stage(1, 1);
    int buf = 0;
    const int rsw = l31 & 7;              // read-side swizzle key (row&7)

    for (int t = 0; t < NT; ++t) {
        // tile t's 3 loads retired; tile t+1's 3 stay in flight
        asm volatile("s_waitcnt vmcnt(3)" ::: "memory");
        __builtin_amdgcn_s_barrier();
        asm volatile("" ::: "memory");

        {   // prefetch tile t+2 (wraps at the tail: harmless refetch)
            int nt2 = t + 2; if (nt2 >= NT) nt2 -= NT;
            int nb  = buf + 2; if (nb >= 3) nb -= 3;
            stage(nt2, nb);
        }

        const _Float16* Kl = SMEM + buf * 8192;
        const _Float16* Vl = Kl + 4096;
        const float*    Mw = Ms[buf][wave];

        // ---- sc init = mask bias (C-operand), keys wk*32 + row_l(r) ----
        float4 mm0 = *reinterpret_cast<const float4*>(&Mw[wk * 32 + 0 + kg * 4]);
        float4 mm1 = *reinterpret_cast<const float4*>(&Mw[wk * 32 + 8 + kg * 4]);
        float4 mm2 = *reinterpret_cast<const float4*>(&Mw[wk * 32 + 16 + kg * 4]);
        float4 mm3 = *reinterpret_cast<const float4*>(&Mw[wk * 32 + 24 + kg * 4]);
        f32x16 sc = { mm0.x, mm0.y, mm0.z, mm0.w,
                      mm1.x, mm1.y, mm1.z, mm1.w,
                      mm2.x, mm2.y, mm2.z, mm2.w,
                      mm3.x, mm3.y, mm3.z, mm3.w };

        // ---- S^T = K.Q^T + bias : 4 chained 32x32x16 on this wave's keys --
        const _Float16* Krow = &Kl[(wk * 32 + l31) * 64];
        half8 kf[4];
        #pragma unroll
        for (int kc = 0; kc < 4; ++kc)
            kf[kc] = *reinterpret_cast<const half8*>(
                &Krow[((kc * 2 + kg) ^ rsw) * 8]);
        __builtin_amdgcn_s_setprio(1);
        #pragma unroll
        for (int kc = 0; kc < 4; ++kc)
            sc = __builtin_amdgcn_mfma_f32_32x32x16_f16(kf[kc], qf[kc], sc, 0, 0, 0);
        __builtin_amdgcn_s_setprio(0);

        // ---- V fragments: chunks of this wave's 32 keys ----
        half8 vf[2][2];
        #pragma unroll
        for (int dt = 0; dt < 2; ++dt) {
            const _Float16* Vrow = &Vl[(dt * 32 + l31) * 64];
            #pragma unroll
            for (int hh = 0; hh < 2; ++hh)
                vf[dt][hh] = *reinterpret_cast<const half8*>(
                    &Vrow[((wk * 4 + hh * 2 + kg) ^ rsw) * 8]);
        }

        // ---- p = 2^sc ; den ; in-register P^T frags ; PV ----
        float p[16];
        #pragma unroll
        for (int r = 0; r < 16; ++r)
            p[r] = __builtin_amdgcn_exp2f(sc[r]);
        den += (((p[0] + p[1]) + (p[2] + p[3])) +
                ((p[4] + p[5]) + (p[6] + p[7]))) +
               (((p[8] + p[9]) + (p[10] + p[11])) +
                ((p[12] + p[13]) + (p[14] + p[15])));

        #pragma unroll
        for (int hh = 0; hh < 2; ++hh) {
            unsigned a0 = __builtin_bit_cast(unsigned,
                __builtin_amdgcn_cvt_pkrtz(p[hh * 8 + 0], p[hh * 8 + 1]));
            unsigned a1 = __builtin_bit_cast(unsigned,
                __builtin_amdgcn_cvt_pkrtz(p[hh * 8 + 2], p[hh * 8 + 3]));
            unsigned b0 = __builtin_bit_cast(unsigned,
                __builtin_amdgcn_cvt_pkrtz(p[hh * 8 + 4], p[hh * 8 + 5]));
            unsigned b1 = __builtin_bit_cast(unsigned,
                __builtin_amdgcn_cvt_pkrtz(p[hh * 8 + 6], p[hh * 8 + 7]));
            permlane32_swap(a0, b0);   // a0 = d0, b0 = d2
            permlane32_swap(a1, b1);   // a1 = d1, b1 = d3
            uint4v pd = { a0, a1, b0, b1 };
            half8 pf = __builtin_bit_cast(half8, pd);
            __builtin_amdgcn_s_setprio(1);
            acc[0] = __builtin_amdgcn_mfma_f32_32x32x16_f16(
                vf[0][hh], pf, acc[0], 0, 0, 0);
            acc[1] = __builtin_amdgcn_mfma_f32_32x32x16_f16(
                vf[1][hh], pf, acc[1], 0, 0, 0);
            __builtin_amdgcn_s_setprio(0);
        }
        if (++buf == 3) buf = 0;
    }

    // ---- combine the two key-halves through dead staging LDS ----
    asm volatile("s_waitcnt vmcnt(0)" ::: "memory");   // tail DMAs landed
    __syncthreads();

    den += __shfl_xor(den, 32, 64);     // combine kg halves (both hold q=l31)

    float* LF = reinterpret_cast<float*>(SMEM);        // 12288 floats avail
    float* DF = reinterpret_cast<float*>(Ms);
    if (wk == 1) {
        float* wbase = LF + (wq * 64 + lane) * 36;     // pad 36: bank spread
        #pragma unroll
        for (int dt = 0; dt < 2; ++dt)
            #pragma unroll
            for (int g = 0; g < 4; ++g) {
                float4 o = { acc[dt][g * 4 + 0], acc[dt][g * 4 + 1],
                             acc[dt][g * 4 + 2], acc[dt][g * 4 + 3] };
                *reinterpret_cast<float4*>(&wbase[dt * 16 + g * 4]) = o;
            }
        if (kg == 0) DF[wq * 32 + l31] = den;
    }
    __syncthreads();
    if (wk == 0) {
        const float* rbase = LF + (wq * 64 + lane) * 36;
        const float inv = 1.0f / (den + DF[wq * 32 + l31]);
        float* orow = Out + ((size_t)(b * S_LEN + qrow)) * HID + h * HDIM;
        #pragma unroll
        for (int dt = 0; dt < 2; ++dt)
            #pragma unroll
            for (int g = 0; g < 4; ++g) {
                float4 pv = *reinterpret_cast<const float4*>(
                    &rbase[dt * 16 + g * 4]);
                float4 o = { (acc[dt][g * 4 + 0] + pv.x) * inv,
                             (acc[dt][g * 4 + 1] + pv.y) * inv,
                             (acc[dt][g * 4 + 2] + pv.z) * inv,
                             (acc[dt][g * 4 + 3] + pv.w) * inv };
                *reinterpret_cast<float4*>(&orow[dt * 32 + g * 8 + kg * 4]) = o;
            }
    }
}

// ---------------------------------------------------------------------------
extern "C" void kernel_launch(void* const* d_in, const int* in_sizes, int n_in,
                              void* d_out, int out_size, void* d_ws, size_t ws_size,
                              hipStream_t stream) {
    const float* X  = (const float*)d_in[0];
    const int*   mk = (const int*)  d_in[1];
    const float* Wq = (const float*)d_in[2];
    const float* bq = (const float*)d_in[3];
    const float* Wk = (const float*)d_in[4];
    const float* bk = (const float*)d_in[5];
    const float* Wv = (const float*)d_in[6];
    const float* bv = (const float*)d_in[7];
    float* out = (float*)d_out;

    // ws (halves): [Xh 4M][Wqh 1M][Wkh 1M][Wvh 1M][Q 4M][K 4M][Vt 4M][maskF]
    _Float16* Xh  = (_Float16*)d_ws;
    _Float16* Wqh = Xh  + (size_t)M_ROWS * HID;
    _Float16* Wkh = Wqh + (size_t)HID * HID;
    _Float16* Wvh = Wkh + (size_t)HID * HID;
    _Float16* Q   = Wvh + (size_t)HID * HID;
    _Float16* K   = Q   + (size_t)BH * S_LEN * HDIM;
    _Float16* Vt  = K   + (size_t)BH * S_LEN * HDIM;
    float*    maskF = (float*)(Vt + (size_t)BH * S_LEN * HDIM);

    cvt_kernel<<<3586, 256, 0, stream>>>(X, Wq, Wk, Wv, mk, Xh, Wqh, Wkh, Wvh, maskF);

    qkv_proj_kernel<<<768, 256, 0, stream>>>(Xh, Wqh, Wkh, Wvh, bq, bk, bv, Q, K, Vt);

    attn_kernel<<<512, 512, 0, stream>>>(Q, K, Vt, maskF, out);
}

// Round 14
// 167.284 us; speedup vs baseline: 1.4516x; 1.0231x over previous
//
#include <hip/hip_runtime.h>
#include <hip/hip_fp16.h>

constexpr int S_LEN  = 2048;
constexpr int HID    = 1024;
constexpr int HEADS  = 16;
constexpr int HDIM   = 64;
constexpr int BATCH  = 2;
constexpr int BH     = BATCH * HEADS;          // 32
constexpr int M_ROWS = BATCH * S_LEN;          // 4096

typedef _Float16 half8  __attribute__((ext_vector_type(8)));
typedef _Float16 half4v __attribute__((ext_vector_type(4)));
typedef _Float16 half2v __attribute__((ext_vector_type(2)));
typedef float    f32x4  __attribute__((ext_vector_type(4)));
typedef float    f32x16 __attribute__((ext_vector_type(16)));
typedef unsigned uint4v __attribute__((ext_vector_type(4)));

constexpr float EXP2_OFF = -11.541560327111707f;   // -8*log2(e)
constexpr float Q_SCALE  = 0.18033688011112042f;   // 0.125*log2(e)

// ---------------------------------------------------------------------------
// Kernel 0: fp32 -> fp16 convert for X, Wq, Wk, Wv; mask -> fp32 exp2-bias.
// ---------------------------------------------------------------------------
__global__ __launch_bounds__(256) void cvt_kernel(
    const float* __restrict__ X,  const float* __restrict__ Wq,
    const float* __restrict__ Wk, const float* __restrict__ Wv,
    const int* __restrict__ mask,
    _Float16* __restrict__ Xh,  _Float16* __restrict__ Wqh,
    _Float16* __restrict__ Wkh, _Float16* __restrict__ Wvh,
    float* __restrict__ maskF)
{
    const int blk = blockIdx.x;
    if (blk >= 3584) {                       // mask: 2 blocks x 2048 elements
        const int loc = blk - 3584;
        const size_t e = ((size_t)loc * 256 + threadIdx.x) * 8;
        #pragma unroll
        for (int i = 0; i < 8; ++i)
            maskF[e + i] = mask[e + i] ? EXP2_OFF : -1.0e30f;
        return;
    }
    const float* src; _Float16* dst; int loc;
    if (blk < 2048)      { src = X;  dst = Xh;  loc = blk; }
    else if (blk < 2560) { src = Wq; dst = Wqh; loc = blk - 2048; }
    else if (blk < 3072) { src = Wk; dst = Wkh; loc = blk - 2560; }
    else                 { src = Wv; dst = Wvh; loc = blk - 3072; }
    const size_t e = ((size_t)loc * 256 + threadIdx.x) * 8;
    float4 a = *reinterpret_cast<const float4*>(&src[e]);
    float4 b = *reinterpret_cast<const float4*>(&src[e + 4]);
    half8 h = { (_Float16)a.x, (_Float16)a.y, (_Float16)a.z, (_Float16)a.w,
                (_Float16)b.x, (_Float16)b.y, (_Float16)b.z, (_Float16)b.w };
    *reinterpret_cast<half8*>(&dst[e]) = h;
}

// ---------------------------------------------------------------------------
__device__ __forceinline__ void async_cp16(_Float16* lds, const _Float16* g) {
    __builtin_amdgcn_global_load_lds(
        (const __attribute__((address_space(1))) void*)g,
        (__attribute__((address_space(3))) void*)lds, 16, 0, 0);
}
__device__ __forceinline__ void async_cp4(float* lds, const float* g) {
    __builtin_amdgcn_global_load_lds(
        (const __attribute__((address_space(1))) void*)g,
        (__attribute__((address_space(3))) void*)lds, 4, 0, 0);
}

// v_permlane32_swap_b32: swaps lanes[32:63] of x with lanes[0:31] of y.
// NOTE: each executed permlane shows up as 8 cycles in SQ_LDS_BANK_CONFLICT
// (crossbar artifact) — attn's constant 4.19M there is NOT ds_read contention.
__device__ __forceinline__ void permlane32_swap(unsigned &x, unsigned &y) {
    asm("v_permlane32_swap_b32 %0, %1" : "+v"(x), "+v"(y));
}

// ---------------------------------------------------------------------------
// Kernel A: QKV projection.  Counted-vmcnt 3-buffer pipeline (verified r8/r12)
//   + conflict-free chunk swizzle g(row) = (row + (row>>2)) & 3 (verified
//   r13: SQ_LDS_BANK_CONFLICT 9.6M -> 164K).  Grid REVERTED to r12's 3D
//   form: r13's XCD remap doubled FETCH (33.9 -> 70.9 MB) by sweeping all
//   32 X-panels per XCD (8 MB > 4 MB L2); the 3D grid's concurrent working
//   set (~4 X-panels + ~3 W-panels ~= 1.8 MB) L2-fits.
// ---------------------------------------------------------------------------
__global__ __launch_bounds__(256) void qkv_proj_kernel(
    const _Float16* __restrict__ Xh,
    const _Float16* __restrict__ Wqh, const _Float16* __restrict__ Wkh,
    const _Float16* __restrict__ Wvh,
    const float* __restrict__ bq, const float* __restrict__ bk,
    const float* __restrict__ bv,
    _Float16* __restrict__ Qo, _Float16* __restrict__ Ko,
    _Float16* __restrict__ Vt)
{
    const int mode = blockIdx.z;
    const _Float16* W    = (mode == 0) ? Wqh : (mode == 1) ? Wkh : Wvh;
    const float*    bias = (mode == 0) ? bq  : (mode == 1) ? bk  : bv;

    const int m0 = blockIdx.x * 128, n0 = blockIdx.y * 128;
    const int tid = threadIdx.x, wave = tid >> 6, lane = tid & 63;
    const int l31 = lane & 31, kg = lane >> 5;      // kg: k-half group (0/1)

    __shared__ _Float16 SMEM[24576];   // 48 KB: 3 bufs x (As 4096 | Bs 4096)

    f32x16 acc[2][2];
    #pragma unroll
    for (int mt = 0; mt < 2; ++mt)
        #pragma unroll
        for (int nt = 0; nt < 2; ++nt)
            #pragma unroll
            for (int i = 0; i < 16; ++i) acc[mt][nt][i] = 0.f;

    const int wm = (wave & 1) * 64, wn = (wave >> 1) * 64;

    const int srow = tid >> 2, spos = tid & 3;
    auto stage = [&](int k0, int b) {
        _Float16* Asb = SMEM + b * 8192;
        _Float16* Bsb = Asb + 4096;
        #pragma unroll
        for (int j = 0; j < 2; ++j) {
            const int row = srow + j * 64;
            const int sch = spos ^ ((row + (row >> 2)) & 3);
            async_cp16(&Asb[j * 2048 + tid * 8],
                       &Xh[(size_t)(m0 + row) * HID + k0 + sch * 8]);
            async_cp16(&Bsb[j * 2048 + tid * 8],
                       &W [(size_t)(n0 + row) * HID + k0 + sch * 8]);
        }
    };

    constexpr int NIT = HID / 32;       // 32 iterations
    stage(0, 0);
    stage(32, 1);
    int buf = 0;

    for (int it = 0; it < NIT; ++it) {
        asm volatile("s_waitcnt vmcnt(4)" ::: "memory");
        __builtin_amdgcn_s_barrier();
        asm volatile("" ::: "memory");

        {   // prefetch tile it+2 (wrap refetch at the tail: harmless)
            int it2 = it + 2; if (it2 >= NIT) it2 -= NIT;
            int nb  = buf + 2; if (nb >= 3) nb -= 3;
            stage(it2 * 32, nb);
        }

        _Float16* Asb = SMEM + buf * 8192;
        _Float16* Bsb = Asb + 4096;

        #pragma unroll
        for (int c = 0; c < 2; ++c) {               // two k-16 chunks
            const int k8 = c * 2 + kg;              // 16B chunk idx (0..3)
            half8 af[2], bf[2];
            #pragma unroll
            for (int mt = 0; mt < 2; ++mt) {
                const int row = wm + mt * 32 + l31;
                const int g   = (row + (row >> 2)) & 3;
                af[mt] = *reinterpret_cast<const half8*>(
                    &Asb[row * 32 + ((k8 ^ g) * 8)]);
            }
            #pragma unroll
            for (int nt = 0; nt < 2; ++nt) {
                const int row = wn + nt * 32 + l31;
                const int g   = (row + (row >> 2)) & 3;
                bf[nt] = *reinterpret_cast<const half8*>(
                    &Bsb[row * 32 + ((k8 ^ g) * 8)]);
            }
            __builtin_amdgcn_s_setprio(1);
            #pragma unroll
            for (int mt = 0; mt < 2; ++mt)
                #pragma unroll
                for (int nt = 0; nt < 2; ++nt)
                    acc[mt][nt] = __builtin_amdgcn_mfma_f32_32x32x16_f16(
                        af[mt], bf[nt], acc[mt][nt], 0, 0, 0);
            __builtin_amdgcn_s_setprio(0);
        }
        if (++buf == 3) buf = 0;
    }
    // wrapped refetch DMAs must land before SMEM is reused as T
    asm volatile("s_waitcnt vmcnt(0)" ::: "memory");
    __syncthreads();

    _Float16* T = SMEM + wave * 4608;      // wave-private [64][72]

    const int nn  = n0 + wn;               // 64-aligned -> single head
    const int hh  = nn >> 6;
    const int mm  = m0 + wm;               // 64-aligned -> single batch
    const int bb  = mm >> 11;
    const int bhv = bb * HEADS + hh;
    const int s0  = mm & 2047;
    const int rowg = lane >> 3, chunk = lane & 7;   // store-phase mapping

    if (mode < 2) {
        _Float16* Out = (mode == 0) ? Qo : Ko;
        #pragma unroll
        for (int nt = 0; nt < 2; ++nt) {
            const int col = nt * 32 + l31;
            float bias_n = bias[nn + col];
            #pragma unroll
            for (int mt = 0; mt < 2; ++mt)
                #pragma unroll
                for (int r = 0; r < 16; ++r) {
                    const int row_l = (r & 3) + 8 * (r >> 2) + 4 * kg;
                    float v = acc[mt][nt][r] + bias_n;
                    if (mode == 0) v *= Q_SCALE;
                    T[(mt * 32 + row_l) * 72 + col] = (_Float16)v;
                }
        }
        asm volatile("s_waitcnt lgkmcnt(0)" ::: "memory");   // wave-private
        #pragma unroll
        for (int j = 0; j < 8; ++j) {
            const int sr = j * 8 + rowg;
            half8 v = *reinterpret_cast<const half8*>(&T[sr * 72 + chunk * 8]);
            *reinterpret_cast<half8*>(
                &Out[((size_t)bhv * S_LEN + s0 + sr) * HDIM + chunk * 8]) = v;
        }
    } else {
        #pragma unroll
        for (int nt = 0; nt < 2; ++nt) {
            const int col = nt * 32 + l31;
            const float bias_n = bias[nn + col];
            #pragma unroll
            for (int mt = 0; mt < 2; ++mt)
                #pragma unroll
                for (int rg = 0; rg < 4; ++rg) {
                    half4v t = { (_Float16)(acc[mt][nt][rg * 4 + 0] + bias_n),
                                 (_Float16)(acc[mt][nt][rg * 4 + 1] + bias_n),
                                 (_Float16)(acc[mt][nt][rg * 4 + 2] + bias_n),
                                 (_Float16)(acc[mt][nt][rg * 4 + 3] + bias_n) };
                    const int s_off = mt * 32 + 8 * rg + 4 * kg;
                    *reinterpret_cast<half4v*>(&T[col * 72 + s_off]) = t;
                }
        }
        asm volatile("s_waitcnt lgkmcnt(0)" ::: "memory");   // wave-private
        #pragma unroll
        for (int j = 0; j < 8; ++j) {
            const int dr = j * 8 + rowg;
            half8 v = *reinterpret_cast<const half8*>(&T[dr * 72 + chunk * 8]);
            *reinterpret_cast<half8*>(
                &Vt[((size_t)bhv * HDIM + dr) * S_LEN + s0 + chunk * 8]) = v;
        }
    }
}

// ---------------------------------------------------------------------------
// Kernel B: attention = r6/r12 structure EXACTLY (best measured: 50.4 us).
//   512 blocks x 512 thr, 8 waves (wq x wk in-block key-split), C-init =
//   mask bias from LDS, counted vmcnt(3) + raw s_barrier, 3-buf staging,
//   in-register P (cvt_pkrtz + permlane32_swap), setprio around MFMA.
//   Rejected by experiment: T15 reg-pipeline (r10: spill, 129 us),
//   mask-from-global (r8: +traffic), literal-idx unroll (r11: miscompile).
// ---------------------------------------------------------------------------
__global__ __launch_bounds__(512, 4) void attn_kernel(
    const _Float16* __restrict__ Q, const _Float16* __restrict__ K,
    const _Float16* __restrict__ Vt, const float* __restrict__ maskF,
    float* __restrict__ Out)
{
    const int id   = blockIdx.x;                    // 0..511
    const int xcd  = id & 7;
    const int bh   = xcd * 4 + ((id >> 3) & 3);     // 4 bh per XCD
    const int qt   = id >> 5;                       // 0..15
    const int b = bh >> 4, h = bh & 15;
    const int tid = threadIdx.x, wave = tid >> 6, lane = tid & 63;
    const int l31 = lane & 31, kg = lane >> 5;
    const int wq = wave & 3, wk = wave >> 2;

    __shared__ _Float16 SMEM[3 * 8192];   // 48 KB: 3 bufs x (K 64x64 | V 64x64)
    __shared__ float    Ms[3][8][64];     // 6 KB wave-private mask tiles

    const _Float16* Qb = Q  + (size_t)bh * S_LEN * HDIM;
    const _Float16* Kb = K  + (size_t)bh * S_LEN * HDIM;
    const _Float16* Vb = Vt + (size_t)bh * HDIM * S_LEN;
    const float*    mb = maskF + b * S_LEN;

    const int qrow = qt * 128 + wq * 32 + l31;

    half8 qf[4];
    #pragma unroll
    for (int kc = 0; kc < 4; ++kc)
        qf[kc] = *reinterpret_cast<const half8*>(
            &Qb[(size_t)qrow * HDIM + kc * 16 + kg * 8]);
    // retire qf BEFORE any staging so the DMA queue count stays clean
    asm volatile("s_waitcnt vmcnt(0)" ::: "memory");

    f32x16 acc[2];
    #pragma unroll
    for (int dt = 0; dt < 2; ++dt)
        #pragma unroll
        for (int i = 0; i < 16; ++i) acc[dt][i] = 0.f;
    float den = 0.f;

    // staging: 512 threads cover a full 64x64 tile per array: 1 cp16 each.
    // Per wave exactly 3 VMEM instrs/stage: K cp16 + V cp16 + mask cp4.
    const int srow = tid >> 3;                            // 0..63
    const int slot = tid & 7;
    auto stage = [&](int tile, int bufsel) {
        const int kb   = tile * 64;
        const int csrc = slot ^ (srow & 7);
        _Float16* Kd = SMEM + bufsel * 8192;
        async_cp16(&Kd[tid * 8], &Kb[(size_t)(kb + srow) * HDIM + csrc * 8]);
        async_cp16(&Kd[4096 + tid * 8],
                   &Vb[(size_t)srow * S_LEN + kb + csrc * 8]);
        async_cp4(&Ms[bufsel][wave][lane], &mb[kb + lane]);
    };

    constexpr int NT = S_LEN / 64;        // 32 tiles
    stage(0, 0);
    stage(1, 1);
    int buf = 0;
    const int rsw = l31 & 7;              // read-side swizzle key (row&7)

    for (int t = 0; t < NT; ++t) {
        // tile t's 3 loads retired; tile t+1's 3 stay in flight
        asm volatile("s_waitcnt vmcnt(3)" ::: "memory");
        __builtin_amdgcn_s_barrier();
        asm volatile("" ::: "memory");

        {   // prefetch tile t+2 (wraps at the tail: harmless refetch)
            int nt2 = t + 2; if (nt2 >= NT) nt2 -= NT;
            int nb  = buf + 2; if (nb >= 3) nb -= 3;
            stage(nt2, nb);
        }

        const _Float16* Kl = SMEM + buf * 8192;
        const _Float16* Vl = Kl + 4096;
        const float*    Mw = Ms[buf][wave];

        // ---- sc init = mask bias (C-operand), keys wk*32 + row_l(r) ----
        float4 mm0 = *reinterpret_cast<const float4*>(&Mw[wk * 32 + 0 + kg * 4]);
        float4 mm1 = *reinterpret_cast<const float4*>(&Mw[wk * 32 + 8 + kg * 4]);
        float4 mm2 = *reinterpret_cast<const float4*>(&Mw[wk * 32 + 16 + kg * 4]);
        float4 mm3 = *reinterpret_cast<const float4*>(&Mw[wk * 32 + 24 + kg * 4]);
        f32x16 sc = { mm0.x, mm0.y, mm0.z, mm0.w,
                      mm1.x, mm1.y, mm1.z, mm1.w,
                      mm2.x, mm2.y, mm2.z, mm2.w,
                      mm3.x, mm3.y, mm3.z, mm3.w };

        // ---- S^T = K.Q^T + bias : 4 chained 32x32x16 on this wave's keys --
        const _Float16* Krow = &Kl[(wk * 32 + l31) * 64];
        half8 kf[4];
        #pragma unroll
        for (int kc = 0; kc < 4; ++kc)
            kf[kc] = *reinterpret_cast<const half8*>(
                &Krow[((kc * 2 + kg) ^ rsw) * 8]);
        __builtin_amdgcn_s_setprio(1);
        #pragma unroll
        for (int kc = 0; kc < 4; ++kc)
            sc = __builtin_amdgcn_mfma_f32_32x32x16_f16(kf[kc], qf[kc], sc, 0, 0, 0);
        __builtin_amdgcn_s_setprio(0);

        // ---- V fragments: chunks of this wave's 32 keys ----
        half8 vf[2][2];
        #pragma unroll
        for (int dt = 0; dt < 2; ++dt) {
            const _Float16* Vrow = &Vl[(dt * 32 + l31) * 64];
            #pragma unroll
            for (int hh = 0; hh < 2; ++hh)
                vf[dt][hh] = *reinterpret_cast<const half8*>(
                    &Vrow[((wk * 4 + hh * 2 + kg) ^ rsw) * 8]);
        }

        // ---- p = 2^sc ; den ; in-register P^T frags ; PV ----
        float p[16];
        #pragma unroll
        for (int r = 0; r < 16; ++r)
            p[r] = __builtin_amdgcn_exp2f(sc[r]);
        den += (((p[0] + p[1]) + (p[2] + p[3])) +
                ((p[4] + p[5]) + (p[6] + p[7]))) +
               (((p[8] + p[9]) + (p[10] + p[11])) +
                ((p[12] + p[13]) + (p[14] + p[15])));

        #pragma unroll
        for (int hh = 0; hh < 2; ++hh) {
            unsigned a0 = __builtin_bit_cast(unsigned,
                __builtin_amdgcn_cvt_pkrtz(p[hh * 8 + 0], p[hh * 8 + 1]));
            unsigned a1 = __builtin_bit_cast(unsigned,
                __builtin_amdgcn_cvt_pkrtz(p[hh * 8 + 2], p[hh * 8 + 3]));
            unsigned b0 = __builtin_bit_cast(unsigned,
                __builtin_amdgcn_cvt_pkrtz(p[hh * 8 + 4], p[hh * 8 + 5]));
            unsigned b1 = __builtin_bit_cast(unsigned,
                __builtin_amdgcn_cvt_pkrtz(p[hh * 8 + 6], p[hh * 8 + 7]));
            permlane32_swap(a0, b0);   // a0 = d0, b0 = d2
            permlane32_swap(a1, b1);   // a1 = d1, b1 = d3
            uint4v pd = { a0, a1, b0, b1 };
            half8 pf = __builtin_bit_cast(half8, pd);
            __builtin_amdgcn_s_setprio(1);
            acc[0] = __builtin_amdgcn_mfma_f32_32x32x16_f16(
                vf[0][hh], pf, acc[0], 0, 0, 0);
            acc[1] = __builtin_amdgcn_mfma_f32_32x32x16_f16(
                vf[1][hh], pf, acc[1], 0, 0, 0);
            __builtin_amdgcn_s_setprio(0);
        }
        if (++buf == 3) buf = 0;
    }

    // ---- combine the two key-halves through dead staging LDS ----
    asm volatile("s_waitcnt vmcnt(0)" ::: "memory");   // tail DMAs landed
    __syncthreads();

    den += __shfl_xor(den, 32, 64);     // combine kg halves (both hold q=l31)

    float* LF = reinterpret_cast<float*>(SMEM);        // 12288 floats avail
    float* DF = reinterpret_cast<float*>(Ms);
    if (wk == 1) {
        float* wbase = LF + (wq * 64 + lane) * 36;     // pad 36: bank spread
        #pragma unroll
        for (int dt = 0; dt < 2; ++dt)
            #pragma unroll
            for (int g = 0; g < 4; ++g) {
                float4 o = { acc[dt][g * 4 + 0], acc[dt][g * 4 + 1],
                             acc[dt][g * 4 + 2], acc[dt][g * 4 + 3] };
                *reinterpret_cast<float4*>(&wbase[dt * 16 + g * 4]) = o;
            }
        if (kg == 0) DF[wq * 32 + l31] = den;
    }
    __syncthreads();
    if (wk == 0) {
        const float* rbase = LF + (wq * 64 + lane) * 36;
        const float inv = 1.0f / (den + DF[wq * 32 + l31]);
        float* orow = Out + ((size_t)(b * S_LEN + qrow)) * HID + h * HDIM;
        #pragma unroll
        for (int dt = 0; dt < 2; ++dt)
            #pragma unroll
            for (int g = 0; g < 4; ++g) {
                float4 pv = *reinterpret_cast<const float4*>(
                    &rbase[dt * 16 + g * 4]);
                float4 o = { (acc[dt][g * 4 + 0] + pv.x) * inv,
                             (acc[dt][g * 4 + 1] + pv.y) * inv,
                             (acc[dt][g * 4 + 2] + pv.z) * inv,
                             (acc[dt][g * 4 + 3] + pv.w) * inv };
                *reinterpret_cast<float4*>(&orow[dt * 32 + g * 8 + kg * 4]) = o;
            }
    }
}

// ---------------------------------------------------------------------------
extern "C" void kernel_launch(void* const* d_in, const int* in_sizes, int n_in,
                              void* d_out, int out_size, void* d_ws, size_t ws_size,
                              hipStream_t stream) {
    const float* X  = (const float*)d_in[0];
    const int*   mk = (const int*)  d_in[1];
    const float* Wq = (const float*)d_in[2];
    const float* bq = (const float*)d_in[3];
    const float* Wk = (const float*)d_in[4];
    const float* bk = (const float*)d_in[5];
    const float* Wv = (const float*)d_in[6];
    const float* bv = (const float*)d_in[7];
    float* out = (float*)d_out;

    // ws (halves): [Xh 4M][Wqh 1M][Wkh 1M][Wvh 1M][Q 4M][K 4M][Vt 4M][maskF]
    _Float16* Xh  = (_Float16*)d_ws;
    _Float16* Wqh = Xh  + (size_t)M_ROWS * HID;
    _Float16* Wkh = Wqh + (size_t)HID * HID;
    _Float16* Wvh = Wkh + (size_t)HID * HID;
    _Float16* Q   = Wvh + (size_t)HID * HID;
    _Float16* K   = Q   + (size_t)BH * S_LEN * HDIM;
    _Float16* Vt  = K   + (size_t)BH * S_LEN * HDIM;
    float*    maskF = (float*)(Vt + (size_t)BH * S_LEN * HDIM);

    cvt_kernel<<<3586, 256, 0, stream>>>(X, Wq, Wk, Wv, mk, Xh, Wqh, Wkh, Wvh, maskF);

    dim3 gp(M_ROWS / 128, HID / 128, 3);
    qkv_proj_kernel<<<gp, 256, 0, stream>>>(Xh, Wqh, Wkh, Wvh, bq, bk, bv, Q, K, Vt);

    attn_kernel<<<512, 512, 0, stream>>>(Q, K, Vt, maskF, out);
}